// Round 6
// baseline (281.933 us; speedup 1.0000x reference)
//
#include <hip/hip_runtime.h>
#include <hip/hip_bf16.h>
#include <math.h>

#define NNODES 50000
#define NEDGES 800000
#define INF    128
#define HIDD   32
#define HEADS  8
#define C1     256   // HEADS*HIDD
#define NCLS   40
#define NCP    48    // NCLS padded to 3 MFMA col-tiles
#define NSB    49    // scan blocks: ceil(50000/1024)
#define EB     ((NEDGES / 4 + 255) / 256)   // edge blocks (4 edges/thread)
#define G1B    ((NNODES + 31) / 32)         // gemm1 blocks

typedef unsigned int  uint;
typedef unsigned short ushort;
typedef __attribute__((ext_vector_type(8))) short short8v;   // 8 bf16 (4 VGPRs)
typedef __attribute__((ext_vector_type(4))) float f32x4;

__device__ __forceinline__ float bf2f(ushort v) {
  return __uint_as_float(((uint)v) << 16);
}
__device__ __forceinline__ ushort f2bf(float f) {
  __hip_bfloat16 b = __float2bfloat16(f);
  return *reinterpret_cast<ushort*>(&b);
}
__device__ __forceinline__ float ldv(const void* p, long i, int isf) {
  return isf ? ((const float*)p)[i] : bf2f(((const ushort*)p)[i]);
}
__device__ __forceinline__ uint packbf2(float f0, float f1) {
  return (uint)f2bf(f0) | ((uint)f2bf(f1) << 16);
}
__device__ __forceinline__ float lrelu(float x) {
  return fmaxf(x, 0.2f * x);   // exact for all x (slope<1)
}

// -------- init: zero deg + scan flags + dtype detect -----------------------
__global__ __launch_bounds__(256) void k_init(const ushort* __restrict__ xr,
                                              int* __restrict__ flag,
                                              int* __restrict__ deg,
                                              int* __restrict__ aggf) {
  const int g = blockIdx.x * 256 + threadIdx.x;
  if (g < NNODES) deg[g] = 0;
  if (g < 64) aggf[g] = 0;
  if (blockIdx.x == 0 && threadIdx.x < 64) {
    const int t = threadIdx.x;
    int c = 0;
    for (int i = t; i < 4096; i += 64) {
      const uint e = (xr[i] >> 7) & 0xFFu;
      if (e > 200u) c++;
    }
#pragma unroll
    for (int k = 32; k >= 1; k >>= 1) c += __shfl_xor(c, k, 64);
    if (t == 0) flag[0] = (c > 100) ? 1 : 0;  // 1 => inputs stored as float32
  }
}

// -------- hist (degree+rank) ∥ prep (weight transpose), role-split ---------
__global__ __launch_bounds__(256) void k_histprep(
    const int* __restrict__ dst, int* __restrict__ deg, int* __restrict__ erank,
    const void* __restrict__ W1r, const void* __restrict__ W2r,
    const int* __restrict__ flag,
    ushort* __restrict__ w1tb, ushort* __restrict__ w2tb) {
  const int b = blockIdx.x;
  if (b < EB) {
    const int e = (b * 256 + threadIdx.x) << 2;   // NEDGES % 4 == 0
    if (e < NEDGES) {
      const int4 d4 = *reinterpret_cast<const int4*>(dst + e);
      int4 r4;
      r4.x = atomicAdd(&deg[d4.x], 1);
      r4.y = atomicAdd(&deg[d4.y], 1);
      r4.z = atomicAdd(&deg[d4.z], 1);
      r4.w = atomicAdd(&deg[d4.w], 1);
      *reinterpret_cast<int4*>(erank + e) = r4;
    }
  } else {
    const int pb = b - EB;
    const int isf = flag[0];
    if (pb < INF) {
      const int k = pb, n = threadIdx.x;
      w1tb[(size_t)n * INF + k] = f2bf(ldv(W1r, (long)k * C1 + n, isf));
    } else {
      const int n = pb - INF, k = threadIdx.x;
      w2tb[(size_t)n * C1 + k] =
          (n < NCLS) ? f2bf(ldv(W2r, (long)k * NCLS + n, isf)) : (ushort)0;
    }
  }
}

// -------- single-pass scan: publish aggregates, lookback-sum ---------------
// All NSB=49 blocks are co-resident (49 << 256 CUs) => no deadlock.
__global__ __launch_bounds__(1024) void k_scan(const int* __restrict__ deg,
                                               int* __restrict__ rowptr,
                                               int* __restrict__ aggf) {
  __shared__ int wsum[16];
  __shared__ int base_s;
  const int b = blockIdx.x, t = threadIdx.x;
  const int i = b * 1024 + t;
  const int lane = t & 63, wv = t >> 6;
  const int v = (i < NNODES) ? deg[i] : 0;
  int p = v;
#pragma unroll
  for (int off = 1; off < 64; off <<= 1) {
    int u = __shfl_up(p, off, 64);
    if (lane >= off) p += u;
  }
  if (lane == 63) wsum[wv] = p;
  __syncthreads();
  if (wv == 0) {
    int s = (lane < 16) ? wsum[lane] : 0;
#pragma unroll
    for (int off = 1; off < 16; off <<= 1) {
      int u = __shfl_up(s, off, 64);
      if (lane >= off) s += u;
    }
    if (lane < 16) wsum[lane] = s;
  }
  __syncthreads();
  if (t == 0) atomicExch(&aggf[b], wsum[15] + 1);   // publish total (+1 sentinel)
  if (t < 64) {
    int sum = 0;
    for (int j = lane; j < b; j += 64) {
      int a;
      while ((a = atomicAdd(&aggf[j], 0)) == 0) __builtin_amdgcn_s_sleep(8);
      sum += a - 1;
    }
#pragma unroll
    for (int k = 32; k >= 1; k >>= 1) sum += __shfl_xor(sum, k, 64);
    if (lane == 0) base_s = sum;
  }
  __syncthreads();
  const int wbase = (wv > 0) ? wsum[wv - 1] : 0;
  if (i < NNODES) rowptr[i] = base_s + wbase + p - v;   // exclusive
}

// -------- scatter (atomic-free) ∥ MFMA GEMM1 + fused elr1, role-split ------
__global__ __launch_bounds__(256) void k_scatgemm1(
    const int* __restrict__ src, const int* __restrict__ dst,
    const int* __restrict__ rowptr, const int* __restrict__ erank,
    int* __restrict__ colsrc,
    const void* __restrict__ Xr, const ushort* __restrict__ w1tb,
    const void* __restrict__ alr, const void* __restrict__ arr,
    const int* __restrict__ flag,
    ushort* __restrict__ Hb, float* __restrict__ el, float* __restrict__ er) {
  __shared__ __align__(16) ushort xs[32 * 136];
  const int b = blockIdx.x;
  if (b < EB) {   // ---- scatter role ----
    const int e = (b * 256 + threadIdx.x) << 2;
    if (e < NEDGES) {
      const int4 s4 = *reinterpret_cast<const int4*>(src + e);
      const int4 d4 = *reinterpret_cast<const int4*>(dst + e);
      const int4 r4 = *reinterpret_cast<const int4*>(erank + e);
      colsrc[rowptr[d4.x] + r4.x] = s4.x;
      colsrc[rowptr[d4.y] + r4.y] = s4.y;
      colsrc[rowptr[d4.z] + r4.z] = s4.z;
      colsrc[rowptr[d4.w] + r4.w] = s4.w;
    }
    return;
  }
  // ---- gemm1m role ----
  const int tid = threadIdx.x;
  const int rt  = (b - EB) * 32;
  const int isf = flag[0];

  {
    const int r  = tid >> 4;
    const int c0 = (tid & 15) << 3;
#pragma unroll
    for (int p = 0; p < 2; ++p) {
      const int row  = r + (p << 4);
      const int grow = rt + row;
      uint4 u = make_uint4(0u, 0u, 0u, 0u);
      if (grow < NNODES) {
        if (isf) {
          const float* Xf = (const float*)Xr;
          const float4 a = *reinterpret_cast<const float4*>(Xf + (size_t)grow * INF + c0);
          const float4 b2 = *reinterpret_cast<const float4*>(Xf + (size_t)grow * INF + c0 + 4);
          u.x = packbf2(a.x, a.y);
          u.y = packbf2(a.z, a.w);
          u.z = packbf2(b2.x, b2.y);
          u.w = packbf2(b2.z, b2.w);
        } else {
          const ushort* Xb = (const ushort*)Xr;
          u = *reinterpret_cast<const uint4*>(Xb + (size_t)grow * INF + c0);
        }
      }
      *reinterpret_cast<uint4*>(&xs[row * 136 + c0]) = u;
    }
  }
  __syncthreads();

  const int lane = tid & 63;
  const int wv   = tid >> 6;
  const int n0   = wv << 6;
  const int col  = lane & 15;
  const int quad = lane >> 4;

  short8v bf[16];
#pragma unroll
  for (int ct = 0; ct < 4; ++ct)
#pragma unroll
    for (int ks = 0; ks < 4; ++ks)
      bf[ct * 4 + ks] = *reinterpret_cast<const short8v*>(
          &w1tb[(size_t)(n0 + ct * 16 + col) * INF + (ks << 5) + (quad << 3)]);
  short8v af[8];
#pragma unroll
  for (int rt2 = 0; rt2 < 2; ++rt2)
#pragma unroll
    for (int ks = 0; ks < 4; ++ks)
      af[rt2 * 4 + ks] = *reinterpret_cast<const short8v*>(
          &xs[(rt2 * 16 + col) * 136 + (ks << 5) + (quad << 3)]);

  f32x4 acc[8];
#pragma unroll
  for (int i = 0; i < 8; ++i) acc[i] = (f32x4){0.f, 0.f, 0.f, 0.f};

#pragma unroll
  for (int rt2 = 0; rt2 < 2; ++rt2)
#pragma unroll
    for (int ct = 0; ct < 4; ++ct)
#pragma unroll
      for (int ks = 0; ks < 4; ++ks)
        acc[rt2 * 4 + ct] = __builtin_amdgcn_mfma_f32_16x16x32_bf16(
            af[rt2 * 4 + ks], bf[ct * 4 + ks], acc[rt2 * 4 + ct], 0, 0, 0);

#pragma unroll
  for (int rt2 = 0; rt2 < 2; ++rt2)
#pragma unroll
    for (int ct = 0; ct < 4; ++ct)
#pragma unroll
      for (int r = 0; r < 4; ++r) {
        const int row = rt + rt2 * 16 + (quad << 2) + r;
        if (row < NNODES)
          Hb[(size_t)row * C1 + n0 + (ct << 4) + col] = f2bf(acc[rt2 * 4 + ct][r]);
      }

  float alv[4], arv[4];
#pragma unroll
  for (int ct = 0; ct < 4; ++ct) {
    alv[ct] = ldv(alr, n0 + ct * 16 + col, isf);
    arv[ct] = ldv(arr, n0 + ct * 16 + col, isf);
  }
#pragma unroll
  for (int rt2 = 0; rt2 < 2; ++rt2)
#pragma unroll
    for (int r = 0; r < 4; ++r) {
      float pl0 = acc[rt2 * 4 + 0][r] * alv[0] + acc[rt2 * 4 + 1][r] * alv[1];
      float pl1 = acc[rt2 * 4 + 2][r] * alv[2] + acc[rt2 * 4 + 3][r] * alv[3];
      float pr0 = acc[rt2 * 4 + 0][r] * arv[0] + acc[rt2 * 4 + 1][r] * arv[1];
      float pr1 = acc[rt2 * 4 + 2][r] * arv[2] + acc[rt2 * 4 + 3][r] * arv[3];
#pragma unroll
      for (int k = 1; k <= 8; k <<= 1) {
        pl0 += __shfl_xor(pl0, k, 64);
        pl1 += __shfl_xor(pl1, k, 64);
        pr0 += __shfl_xor(pr0, k, 64);
        pr1 += __shfl_xor(pr1, k, 64);
      }
      if (col == 0) {
        const int row = rt + rt2 * 16 + (quad << 2) + r;
        if (row < NNODES) {
          el[row * HEADS + 2 * wv]     = pl0;
          el[row * HEADS + 2 * wv + 1] = pl1;
          er[row * HEADS + 2 * wv]     = pr0;
          er[row * HEADS + 2 * wv + 1] = pr1;
        }
      }
    }
}

// -------- Agg layer 1: wave/node, 2 edges/wave (half-wave each), uint4 -----
// 32 lanes per edge, 8 cols/lane (16B gather). Exp count halves vs uint2
// version (4 lanes/head instead of 8); gather instr count halves, same bytes.
__global__ __launch_bounds__(256) void k_agg1(const int* __restrict__ rowptr,
                                              const int* __restrict__ deg,
                                              const int* __restrict__ colsrc,
                                              const float* __restrict__ el,
                                              const float* __restrict__ er,
                                              const ushort* __restrict__ h1b,
                                              const void* __restrict__ b1r,
                                              const int* __restrict__ flag,
                                              ushort* __restrict__ out1b) {
  const int n = blockIdx.x * 4 + (threadIdx.x >> 6);
  if (n >= NNODES) return;
  const int lane = threadIdx.x & 63;
  const int half = lane >> 5;        // which edge of the pair
  const int hl   = lane & 31;
  const int c0 = hl << 3;            // 8 cols per lane
  const int h  = hl >> 2;            // head = c0/32
  const int isf = flag[0];
  const int start = rowptr[n];
  const int cnt   = deg[n];
  const char* hp  = (const char*)h1b;
  const char* elp = (const char*)el;
  const float ern = er[n * HEADS + h];
  const int* cp = colsrc + start;
  const uint cb = (uint)c0 << 1;     // byte col offset (2B/col)
  const uint hb = (uint)h << 2;
  float a[8];
#pragma unroll
  for (int k = 0; k < 8; ++k) a[k] = 0.f;
  float den = 0.f;
  int i = 0;
  for (; i + 8 <= cnt; i += 8) {
    int s[4];
#pragma unroll
    for (int j = 0; j < 4; ++j) s[j] = cp[i + (half << 2) + j];
    float l[4];
#pragma unroll
    for (int j = 0; j < 4; ++j)
      l[j] = *reinterpret_cast<const float*>(elp + (((uint)s[j] << 5) | hb));
    uint4 u[4];
#pragma unroll
    for (int j = 0; j < 4; ++j)
      u[j] = *reinterpret_cast<const uint4*>(hp + (((uint)s[j] << 9) | cb));
#pragma unroll
    for (int j = 0; j < 4; ++j) {
      const float e = __expf(lrelu(l[j] + ern));
      den += e;
      a[0] += e * __uint_as_float(u[j].x << 16);
      a[1] += e * __uint_as_float(u[j].x & 0xffff0000u);
      a[2] += e * __uint_as_float(u[j].y << 16);
      a[3] += e * __uint_as_float(u[j].y & 0xffff0000u);
      a[4] += e * __uint_as_float(u[j].z << 16);
      a[5] += e * __uint_as_float(u[j].z & 0xffff0000u);
      a[6] += e * __uint_as_float(u[j].w << 16);
      a[7] += e * __uint_as_float(u[j].w & 0xffff0000u);
    }
  }
  for (; i + 2 <= cnt; i += 2) {     // pairs
    const int s = cp[i + half];
    const float l = *reinterpret_cast<const float*>(elp + (((uint)s << 5) | hb));
    const uint4 u = *reinterpret_cast<const uint4*>(hp + (((uint)s << 9) | cb));
    const float e = __expf(lrelu(l + ern));
    den += e;
    a[0] += e * __uint_as_float(u.x << 16);
    a[1] += e * __uint_as_float(u.x & 0xffff0000u);
    a[2] += e * __uint_as_float(u.y << 16);
    a[3] += e * __uint_as_float(u.y & 0xffff0000u);
    a[4] += e * __uint_as_float(u.z << 16);
    a[5] += e * __uint_as_float(u.z & 0xffff0000u);
    a[6] += e * __uint_as_float(u.w << 16);
    a[7] += e * __uint_as_float(u.w & 0xffff0000u);
  }
  if (i < cnt && half == 0) {        // last odd edge: half 0 only
    const int s = cp[i];
    const float l = *reinterpret_cast<const float*>(elp + (((uint)s << 5) | hb));
    const uint4 u = *reinterpret_cast<const uint4*>(hp + (((uint)s << 9) | cb));
    const float e = __expf(lrelu(l + ern));
    den += e;
    a[0] += e * __uint_as_float(u.x << 16);
    a[1] += e * __uint_as_float(u.x & 0xffff0000u);
    a[2] += e * __uint_as_float(u.y << 16);
    a[3] += e * __uint_as_float(u.y & 0xffff0000u);
    a[4] += e * __uint_as_float(u.z << 16);
    a[5] += e * __uint_as_float(u.z & 0xffff0000u);
    a[6] += e * __uint_as_float(u.w << 16);
    a[7] += e * __uint_as_float(u.w & 0xffff0000u);
  }
  // cross-half reduce (both halves end with full sums)
#pragma unroll
  for (int k = 0; k < 8; ++k) a[k] += __shfl_xor(a[k], 32, 64);
  den += __shfl_xor(den, 32, 64);
  if (half == 0) {
    const float inv = 1.f / fmaxf(den, 1e-9f);
    float o[8];
#pragma unroll
    for (int k = 0; k < 8; ++k) {
      o[k] = a[k] * inv + ldv(b1r, c0 + k, isf);
      o[k] = (o[k] > 0.f) ? o[k] : expm1f(o[k]);
    }
    uint4 w;
    w.x = packbf2(o[0], o[1]);
    w.y = packbf2(o[2], o[3]);
    w.z = packbf2(o[4], o[5]);
    w.w = packbf2(o[6], o[7]);
    *reinterpret_cast<uint4*>((char*)out1b + ((uint)n << 9) + cb) = w;
  }
}

// -------- MFMA GEMM2 + fused elr2: h2[N,40](bf16), el2/er2[N] --------------
__global__ __launch_bounds__(256) void k_gemm2m(const ushort* __restrict__ Ab,
                                                const ushort* __restrict__ w2tb,
                                                const void* __restrict__ alr,
                                                const void* __restrict__ arr,
                                                const int* __restrict__ flag,
                                                ushort* __restrict__ Hb,
                                                float* __restrict__ el,
                                                float* __restrict__ er) {
  __shared__ __align__(16) ushort as2[64 * 264];
  const int tid = threadIdx.x;
  const int rt  = blockIdx.x * 64;
  const int isf = flag[0];

  {
    const int r  = tid >> 2;
    const int cb = (tid & 3) << 6;
    const int grow = rt + r;
#pragma unroll
    for (int j = 0; j < 8; ++j) {
      uint4 u = make_uint4(0u, 0u, 0u, 0u);
      if (grow < NNODES)
        u = *reinterpret_cast<const uint4*>(Ab + (size_t)grow * C1 + cb + (j << 3));
      *reinterpret_cast<uint4*>(&as2[r * 264 + cb + (j << 3)]) = u;
    }
  }
  __syncthreads();

  const int lane = tid & 63;
  const int wv   = tid >> 6;
  const int col  = lane & 15;
  const int quad = lane >> 4;

  f32x4 acc[3];
#pragma unroll
  for (int i = 0; i < 3; ++i) acc[i] = (f32x4){0.f, 0.f, 0.f, 0.f};

#pragma unroll
  for (int ks = 0; ks < 8; ++ks) {
    const int k0 = (ks << 5) + (quad << 3);
    const short8v a = *reinterpret_cast<const short8v*>(&as2[(wv * 16 + col) * 264 + k0]);
    const short8v b0 = *reinterpret_cast<const short8v*>(&w2tb[(size_t)( 0 + col) * C1 + k0]);
    const short8v b1 = *reinterpret_cast<const short8v*>(&w2tb[(size_t)(16 + col) * C1 + k0]);
    const short8v b2 = *reinterpret_cast<const short8v*>(&w2tb[(size_t)(32 + col) * C1 + k0]);
    acc[0] = __builtin_amdgcn_mfma_f32_16x16x32_bf16(a, b0, acc[0], 0, 0, 0);
    acc[1] = __builtin_amdgcn_mfma_f32_16x16x32_bf16(a, b1, acc[1], 0, 0, 0);
    acc[2] = __builtin_amdgcn_mfma_f32_16x16x32_bf16(a, b2, acc[2], 0, 0, 0);
  }

  float alv[3], arv[3];
#pragma unroll
  for (int ct = 0; ct < 3; ++ct) {
    const int gc = ct * 16 + col;
    alv[ct] = (gc < NCLS) ? ldv(alr, gc, isf) : 0.f;
    arv[ct] = (gc < NCLS) ? ldv(arr, gc, isf) : 0.f;
  }
#pragma unroll
  for (int r = 0; r < 4; ++r) {
    const int row = rt + wv * 16 + (quad << 2) + r;
    const bool rok = row < NNODES;
#pragma unroll
    for (int ct = 0; ct < 3; ++ct) {
      const int gc = ct * 16 + col;
      if (rok && gc < NCLS)
        Hb[(size_t)row * NCLS + gc] = f2bf(acc[ct][r]);
    }
    float pl = acc[0][r] * alv[0] + acc[1][r] * alv[1] + acc[2][r] * alv[2];
    float pr = acc[0][r] * arv[0] + acc[1][r] * arv[1] + acc[2][r] * arv[2];
#pragma unroll
    for (int k = 1; k <= 8; k <<= 1) {
      pl += __shfl_xor(pl, k, 64);
      pr += __shfl_xor(pr, k, 64);
    }
    if (col == 0 && rok) {
      el[row] = pl;
      er[row] = pr;
    }
  }
}

// -------- Agg layer 2: QUARTER-WAVE per node, 4 cols/lane (uint2) ----------
// 16 lanes/node: 10 active gather lanes (80B row), 16 exps/edge (was 32).
__global__ __launch_bounds__(256) void k_agg2(const int* __restrict__ rowptr,
                                              const int* __restrict__ deg,
                                              const int* __restrict__ colsrc,
                                              const float* __restrict__ el,
                                              const float* __restrict__ er,
                                              const ushort* __restrict__ h2b,
                                              const void* __restrict__ b2r,
                                              const int* __restrict__ flag,
                                              float* __restrict__ out) {
  const int n = blockIdx.x * 16 + (threadIdx.x >> 4);
  if (n >= NNODES) return;
  const int t  = threadIdx.x & 15;
  const int c0 = t << 2;             // 4 cols per lane
  const bool act = c0 < NCLS;        // lanes 0-9 of 16
  const int isf  = flag[0];
  const int start = rowptr[n];
  const int cnt   = deg[n];
  const float ern = er[n];
  const char* hp = (const char*)h2b;
  const uint cb = (uint)c0 << 1;
  const int* cp = colsrc + start;
  float a0 = 0.f, a1 = 0.f, a2 = 0.f, a3 = 0.f, den = 0.f;
  int i = 0;
  for (; i + 8 <= cnt; i += 8) {
    int s[8];
#pragma unroll
    for (int j = 0; j < 8; ++j) s[j] = cp[i + j];
    float l[8];
#pragma unroll
    for (int j = 0; j < 8; ++j) l[j] = el[s[j]];
    uint2 u[8];
#pragma unroll
    for (int j = 0; j < 8; ++j)
      u[j] = act ? *reinterpret_cast<const uint2*>(hp + (uint)s[j] * 80u + cb)
                 : make_uint2(0u, 0u);
#pragma unroll
    for (int j = 0; j < 8; ++j) {
      const float e = __expf(lrelu(l[j] + ern));
      den += e;
      a0 += e * __uint_as_float(u[j].x << 16);
      a1 += e * __uint_as_float(u[j].x & 0xffff0000u);
      a2 += e * __uint_as_float(u[j].y << 16);
      a3 += e * __uint_as_float(u[j].y & 0xffff0000u);
    }
  }
  for (; i < cnt; ++i) {
    const int s = cp[i];
    const float e = __expf(lrelu(el[s] + ern));
    den += e;
    const uint2 u = act ? *reinterpret_cast<const uint2*>(hp + (uint)s * 80u + cb)
                        : make_uint2(0u, 0u);
    a0 += e * __uint_as_float(u.x << 16);
    a1 += e * __uint_as_float(u.x & 0xffff0000u);
    a2 += e * __uint_as_float(u.y << 16);
    a3 += e * __uint_as_float(u.y & 0xffff0000u);
  }
  if (act) {
    const float inv = 1.f / fmaxf(den, 1e-9f);
    float4 o;
    o.x = a0 * inv + ldv(b2r, c0 + 0, isf);
    o.y = a1 * inv + ldv(b2r, c0 + 1, isf);
    o.z = a2 * inv + ldv(b2r, c0 + 2, isf);
    o.w = a3 * inv + ldv(b2r, c0 + 3, isf);
    *reinterpret_cast<float4*>(out + (size_t)n * NCLS + c0) = o;
  }
}

extern "C" void kernel_launch(void* const* d_in, const int* in_sizes, int n_in,
                              void* d_out, int out_size, void* d_ws, size_t ws_size,
                              hipStream_t stream) {
  // ---- size-driven input mapping ----
  int ix = -1, iW1 = -1, iW2 = -1, e1 = -1, e2 = -1;
  int i256[3] = {-1, -1, -1}, n256 = 0;
  int i40[3]  = {-1, -1, -1}, n40 = 0;
  for (int i = 0; i < n_in; ++i) {
    switch (in_sizes[i]) {
      case 6400000: ix = i; break;
      case 800000:  if (e1 < 0) e1 = i; else e2 = i; break;
      case 32768:   iW1 = i; break;
      case 10240:   iW2 = i; break;
      case 256:     if (n256 < 3) i256[n256++] = i; break;
      case 40:      if (n40 < 3)  i40[n40++]  = i; break;
      default: break;
    }
  }
  bool mapped = (ix >= 0 && iW1 >= 0 && iW2 >= 0 && e2 >= 0 && n256 == 3 && n40 == 3);
  int isrc, idst;
  if (mapped) {
    const bool dict_order = (in_sizes[0] == 6400000);
    isrc = dict_order ? e1 : e2;
    idst = dict_order ? e2 : e1;
  } else {
    ix = 0; isrc = 1; idst = 2; iW1 = 3;
    i256[0] = 4; i256[1] = 5; i256[2] = 6;
    iW2 = 7; i40[0] = 8; i40[1] = 9; i40[2] = 10;
  }
  const void* X   = d_in[ix];
  const int*  src = (const int*)d_in[isrc];
  const int*  dst = (const int*)d_in[idst];
  const void* W1  = d_in[iW1];
  const void* al1 = d_in[i256[0]];
  const void* ar1 = d_in[i256[1]];
  const void* b1  = d_in[i256[2]];
  const void* W2  = d_in[iW2];
  const void* al2 = d_in[i40[0]];
  const void* ar2 = d_in[i40[1]];
  const void* b2  = d_in[i40[2]];

  char* ws = (char*)d_ws;
  size_t off = 0;
  auto alloc = [&](size_t bytes) -> void* {
    void* p = ws + off;
    off = (off + bytes + 255) & ~(size_t)255;
    return p;
  };
  int*    flag   = (int*)alloc(256);
  int*    aggf   = (int*)alloc(64 * 4);
  int*    deg    = (int*)alloc((size_t)NNODES * 4);
  int*    rowptr = (int*)alloc((size_t)NNODES * 4);
  int*    erank  = (int*)alloc((size_t)NEDGES * 4);
  int*    colsrc = (int*)alloc((size_t)NEDGES * 4);
  float*  el1    = (float*)alloc((size_t)NNODES * HEADS * 4);
  float*  er1    = (float*)alloc((size_t)NNODES * HEADS * 4);
  float*  el2    = (float*)alloc((size_t)NNODES * 4);
  float*  er2    = (float*)alloc((size_t)NNODES * 4);
  ushort* w1tb   = (ushort*)alloc((size_t)C1 * INF * 2);
  ushort* w2tb   = (ushort*)alloc((size_t)NCP * C1 * 2);
  ushort* h1b    = (ushort*)alloc((size_t)NNODES * C1 * 2);    // 25.6 MB
  ushort* out1b  = (ushort*)alloc((size_t)NNODES * C1 * 2);    // 25.6 MB
  ushort* h2b    = (ushort*)alloc((size_t)NNODES * NCLS * 2);  // 4 MB

  k_init<<<(NNODES + 255) / 256, 256, 0, stream>>>((const ushort*)X, flag, deg, aggf);
  k_histprep<<<EB + INF + NCP, 256, 0, stream>>>(dst, deg, erank, W1, W2, flag,
                                                 w1tb, w2tb);
  k_scan<<<NSB, 1024, 0, stream>>>(deg, rowptr, aggf);
  k_scatgemm1<<<EB + G1B, 256, 0, stream>>>(src, dst, rowptr, erank, colsrc,
                                            X, w1tb, al1, ar1, flag,
                                            h1b, el1, er1);

  k_agg1<<<(NNODES + 3) / 4, 256, 0, stream>>>(rowptr, deg, colsrc, el1, er1,
                                               h1b, b1, flag, out1b);

  k_gemm2m<<<(NNODES + 63) / 64, 256, 0, stream>>>(out1b, w2tb, al2, ar2, flag,
                                                   h2b, el2, er2);
  k_agg2<<<(NNODES + 15) / 16, 256, 0, stream>>>(rowptr, deg, colsrc, el2, er2,
                                                 h2b, b2, flag, (float*)d_out);
}